// Round 4
// baseline (350.057 us; speedup 1.0000x reference)
//
#include <hip/hip_runtime.h>
#include <hip/hip_bf16.h>
#include <stdint.h>

// ExpanderLinear: y[t,o] = sum_i x[t,i] * (w[o,i]*mask[o,i]) + bias[o]
// M=8192, K=4096, N=4096. f32 in/out, bf16 MFMA compute.
// Flatmm structure: operands pre-shuffled to MFMA-fragment-major layout;
// GEMM loads fragments straight to VGPRs (no LDS, no barriers except pacing),
// register double-buffer 2 k-steps deep, compiler-counted vmcnt.

typedef __attribute__((ext_vector_type(4))) float          f32x4;
typedef __attribute__((ext_vector_type(4))) int            i32x4;
typedef __attribute__((ext_vector_type(8))) unsigned short u16x8;
typedef __attribute__((ext_vector_type(8))) __bf16         bf16x8;

static constexpr int M = 8192;
static constexpr int N = 4096;
static constexpr int K = 4096;
// fragment-major index (ushort): ((R*128 + kk)*64 + lane)*8 + j
//   A: R = row/16 (0..511), kk = k/32 (0..127), lane=(fq<<4)|fr, j=0..7
//      holds x[R*16 + fr][kk*32 + fq*8 + j]   (same for B over out-cols)

__device__ __forceinline__ unsigned short f2bf(float f) {
    unsigned int u = __float_as_uint(f);
    u = (u + 0x7fffu + ((u >> 16) & 1u)) >> 16;
    return (unsigned short)u;
}

// ---- prep 1: x f32 -> bf16, fragment-major ----
__global__ void cvt_x_frag(const float* __restrict__ x,
                           unsigned short* __restrict__ xb) {
    const int g  = blockIdx.x * blockDim.x + threadIdx.x;
    const int ln = g & 63;
    const int w  = g >> 6;
    const int kk = w & 127;
    const int R  = w >> 7;
    const int fr = ln & 15, fq = ln >> 4;
    const float* src = x + (size_t)(R * 16 + fr) * K + kk * 32 + fq * 8;
    f32x4 v0 = *(const f32x4*)src;
    f32x4 v1 = *(const f32x4*)(src + 4);
    u16x8 r;
    r[0] = f2bf(v0.x); r[1] = f2bf(v0.y); r[2] = f2bf(v0.z); r[3] = f2bf(v0.w);
    r[4] = f2bf(v1.x); r[5] = f2bf(v1.y); r[6] = f2bf(v1.z); r[7] = f2bf(v1.w);
    *(u16x8*)(xb + ((size_t)(R * 128 + kk) * 64 + ln) * 8) = r;
}

// ---- prep 2: (w * mask) f32 -> bf16, fragment-major ----
__global__ void cvt_wm_frag(const float* __restrict__ w,
                            const int* __restrict__ mask,
                            unsigned short* __restrict__ wb) {
    const int g  = blockIdx.x * blockDim.x + threadIdx.x;
    const int ln = g & 63;
    const int wv = g >> 6;
    const int kk = wv & 127;
    const int S  = wv >> 7;
    const int fr = ln & 15, fq = ln >> 4;
    const size_t off = (size_t)(S * 16 + fr) * K + kk * 32 + fq * 8;
    f32x4 w0 = *(const f32x4*)(w + off);
    f32x4 w1 = *(const f32x4*)(w + off + 4);
    i32x4 m0 = *(const i32x4*)(mask + off);
    i32x4 m1 = *(const i32x4*)(mask + off + 4);
    u16x8 r;
    r[0] = m0.x ? f2bf(w0.x) : (unsigned short)0;
    r[1] = m0.y ? f2bf(w0.y) : (unsigned short)0;
    r[2] = m0.z ? f2bf(w0.z) : (unsigned short)0;
    r[3] = m0.w ? f2bf(w0.w) : (unsigned short)0;
    r[4] = m1.x ? f2bf(w1.x) : (unsigned short)0;
    r[5] = m1.y ? f2bf(w1.y) : (unsigned short)0;
    r[6] = m1.z ? f2bf(w1.z) : (unsigned short)0;
    r[7] = m1.w ? f2bf(w1.w) : (unsigned short)0;
    *(u16x8*)(wb + ((size_t)(S * 128 + kk) * 64 + ln) * 8) = r;
}

// ---- main GEMM: no LDS, fragment-direct loads, reg double-buffer ----
// 256x256 block tile, 8 waves (2Mx4N), per-wave 128x64 out.
// Per kk-step (K=32): 8 A-frag + 4 B-frag loads (1KB coalesced each), 32 MFMA.
__global__ void __launch_bounds__(512, 2)
gemm_flat(const unsigned short* __restrict__ A,   // frag-major [512][128][64][8]
          const unsigned short* __restrict__ B,   // frag-major [256][128][64][8]
          const float* __restrict__ bias,         // [N]
          float* __restrict__ C) {                // [M][N] f32
    const int tid  = threadIdx.x;
    const int lane = tid & 63;
    const int wave = tid >> 6;

    // T1: XCD-aware bijective swizzle (nwg = 512, % 8 == 0)
    const int bid = blockIdx.x;
    const int swz = (bid & 7) * 64 + (bid >> 3);
    const int brow = (swz >> 4) * 256;
    const int bcol = (swz & 15) * 256;

    const int wrow = (wave >> 2) * 128;
    const int wcol = (wave & 3) * 64;
    const int fr = lane & 15;
    const int fq = lane >> 4;

    const size_t RA0 = (size_t)(brow >> 4) + (wave >> 2) * 8;   // A row-block
    const size_t SB0 = (size_t)(bcol >> 4) + (wave & 3) * 4;    // B col-block
    const unsigned short* __restrict__ Abase = A + RA0 * 65536 + lane * 8;
    const unsigned short* __restrict__ Bbase = B + SB0 * 65536 + lane * 8;

    f32x4 acc[8][4];
#pragma unroll
    for (int m = 0; m < 8; ++m)
#pragma unroll
        for (int n = 0; n < 4; ++n) acc[m][n] = (f32x4)(0.0f);

    bf16x8 a0[8], b0[4], a1[8], b1[4];

#define LDA_(buf, kk) do {                                                      \
    _Pragma("unroll")                                                           \
    for (int m = 0; m < 8; ++m)                                                 \
        buf[m] = *(const bf16x8*)(Abase + (size_t)m * 65536 + (kk) * 512);      \
  } while (0)
#define LDB_(buf, kk) do {                                                      \
    _Pragma("unroll")                                                           \
    for (int n = 0; n < 4; ++n)                                                 \
        buf[n] = *(const bf16x8*)(Bbase + (size_t)n * 65536 + (kk) * 512);      \
  } while (0)
#define MM_(a, b) do {                                                          \
    __builtin_amdgcn_s_setprio(1);                                              \
    _Pragma("unroll")                                                           \
    for (int m = 0; m < 8; ++m)                                                 \
      _Pragma("unroll")                                                         \
      for (int n = 0; n < 4; ++n)                                               \
        acc[m][n] = __builtin_amdgcn_mfma_f32_16x16x32_bf16(                    \
            a[m], b[n], acc[m][n], 0, 0, 0);                                    \
    __builtin_amdgcn_s_setprio(0);                                              \
  } while (0)

    // prologue: steps 0,1 into the two register buffers
    LDA_(a0, 0); LDB_(b0, 0);
    LDA_(a1, 1); LDB_(b1, 1);

    for (int kk = 0; kk < 128; kk += 2) {
        const int p0 = (kk + 2) & 127;   // wraps to 0/1 on last iter: harmless
        const int p1 = (kk + 3) & 127;
        __builtin_amdgcn_s_barrier();    // pacing only (no shared data)
        MM_(a0, b0);
        LDA_(a0, p0); LDB_(b0, p0);
        __builtin_amdgcn_s_barrier();
        MM_(a1, b1);
        LDA_(a1, p1); LDB_(b1, p1);
    }

    // epilogue: C/D layout col=lane&15, row=(lane>>4)*4+reg [m89/m91]
    float bv[4];
#pragma unroll
    for (int n = 0; n < 4; ++n) bv[n] = bias[bcol + wcol + n * 16 + fr];
#pragma unroll
    for (int m = 0; m < 8; ++m) {
#pragma unroll
        for (int j = 0; j < 4; ++j) {
            const int row = brow + wrow + m * 16 + fq * 4 + j;
            float* crow = C + (size_t)row * N + bcol + wcol + fr;
#pragma unroll
            for (int n = 0; n < 4; ++n) crow[n * 16] = acc[m][n][j] + bv[n];
        }
    }
#undef LDA_
#undef LDB_
#undef MM_
}

// ---- fallback (only if ws too small): f32 vector GEMM ----
__global__ void fallback_gemm(const float* __restrict__ x,
                              const float* __restrict__ w,
                              const int* __restrict__ mask,
                              const float* __restrict__ bias,
                              float* __restrict__ C) {
    const int tid = threadIdx.x;
    const int tx = tid & 15, ty = tid >> 4;
    const int brow = blockIdx.y * 64, bcol = blockIdx.x * 64;
    __shared__ float As[64][17];
    __shared__ float Ws[64][17];
    float acc[4][4] = {};
    for (int k0 = 0; k0 < K; k0 += 16) {
        __syncthreads();
        for (int i = tid; i < 64 * 16; i += 256) {
            int r = i >> 4, c = i & 15;
            As[r][c] = x[(size_t)(brow + r) * K + k0 + c];
            float wv = w[(size_t)(bcol + r) * K + k0 + c];
            Ws[r][c] = mask[(size_t)(bcol + r) * K + k0 + c] ? wv : 0.0f;
        }
        __syncthreads();
        for (int kk = 0; kk < 16; ++kk) {
            float a[4], b[4];
#pragma unroll
            for (int i = 0; i < 4; ++i) a[i] = As[ty * 4 + i][kk];
#pragma unroll
            for (int i = 0; i < 4; ++i) b[i] = Ws[tx * 4 + i][kk];
#pragma unroll
            for (int i = 0; i < 4; ++i)
#pragma unroll
                for (int j = 0; j < 4; ++j) acc[i][j] += a[i] * b[j];
        }
    }
    for (int i = 0; i < 4; ++i)
        for (int j = 0; j < 4; ++j) {
            int row = brow + ty * 4 + i, col = bcol + tx * 4 + j;
            C[(size_t)row * N + col] = acc[i][j] + bias[col];
        }
}

extern "C" void kernel_launch(void* const* d_in, const int* in_sizes, int n_in,
                              void* d_out, int out_size, void* d_ws, size_t ws_size,
                              hipStream_t stream) {
    const float* x    = (const float*)d_in[0];
    const float* w    = (const float*)d_in[1];
    const float* bias = (const float*)d_in[2];
    const int*   mask = (const int*)d_in[3];
    float* out = (float*)d_out;

    const size_t need = ((size_t)M * K + (size_t)N * K) * sizeof(unsigned short);
    if (ws_size >= need) {
        unsigned short* xb = (unsigned short*)d_ws;           // frag-major A
        unsigned short* wb = xb + (size_t)M * K;              // frag-major B
        cvt_x_frag<<<(M * K / 8) / 256, 256, 0, stream>>>(x, xb);
        cvt_wm_frag<<<(N * K / 8) / 256, 256, 0, stream>>>(w, mask, wb);
        gemm_flat<<<(M / 256) * (N / 256), 512, 0, stream>>>(xb, wb, bias, out);
    } else {
        dim3 g(N / 64, M / 64);
        fallback_gemm<<<g, 256, 0, stream>>>(x, w, mask, bias, out);
    }
}

// Round 5
// 337.740 us; speedup vs baseline: 1.0365x; 1.0365x over previous
//
#include <hip/hip_runtime.h>
#include <hip/hip_bf16.h>
#include <stdint.h>

// ExpanderLinear: y[t,o] = sum_i x[t,i] * (w[o,i]*mask[o,i]) + bias[o]
// M=8192, K=4096, N=4096. f32 in/out, bf16 MFMA compute.
// GEMM: 256x256 tile, 8 waves, ring-4 half-K LDS units (128 KiB),
// 32x32x16 MFMA, 2 phases/K-tile (16-MFMA clusters), counted vmcnt(4),
// T1 XCD swizzle + T2 LDS swizzle + T5 setprio.

typedef __attribute__((ext_vector_type(4)))  float          f32x4;
typedef __attribute__((ext_vector_type(16))) float          f32x16;
typedef __attribute__((ext_vector_type(4)))  int            i32x4;
typedef __attribute__((ext_vector_type(4)))  unsigned short u16x4;
typedef __attribute__((ext_vector_type(8)))  __bf16         bf16x8;

static constexpr int M = 8192;
static constexpr int N = 4096;
static constexpr int K = 4096;

#define BM 256
#define BN 256
#define NT (K / 64)

#define GLOBAL_AS(p) ((const __attribute__((address_space(1))) void*)(p))
#define LDS_AS(p)    ((__attribute__((address_space(3))) void*)(p))

__device__ __forceinline__ unsigned short f2bf(float f) {
    unsigned int u = __float_as_uint(f);
    u = (u + 0x7fffu + ((u >> 16) & 1u)) >> 16;
    return (unsigned short)u;
}

// ---- prep 1: x f32 -> bf16 (row-major) ----
__global__ void cvt_x_kernel(const float* __restrict__ x,
                             unsigned short* __restrict__ out) {
    int i = blockIdx.x * blockDim.x + threadIdx.x;
    f32x4 v = ((const f32x4*)x)[i];
    u16x4 r;
    r.x = f2bf(v.x); r.y = f2bf(v.y); r.z = f2bf(v.z); r.w = f2bf(v.w);
    ((u16x4*)out)[i] = r;
}

// ---- prep 2: (w * mask) f32 -> bf16, fused (row-major) ----
__global__ void cvt_wm_kernel(const float* __restrict__ w,
                              const int* __restrict__ mask,
                              unsigned short* __restrict__ out) {
    int i = blockIdx.x * blockDim.x + threadIdx.x;
    f32x4 v = ((const f32x4*)w)[i];
    i32x4 m = ((const i32x4*)mask)[i];
    u16x4 r;
    r.x = m.x ? f2bf(v.x) : (unsigned short)0;
    r.y = m.y ? f2bf(v.y) : (unsigned short)0;
    r.z = m.z ? f2bf(v.z) : (unsigned short)0;
    r.w = m.w ? f2bf(v.w) : (unsigned short)0;
    ((u16x4*)out)[i] = r;
}

// ---- main GEMM ----
// LDS: A-ring = 4 units of [256 rows][32 bf16] (16KB each), B-ring same.
// Unit for (tile t, k-half h) at slot (2t+h)&3. Per K-tile: 2 phases, each
// {12 ds_read_b128, 4 global_load_lds, barrier, lgkmcnt(0), 16 MFMA 32x32x16,
//  vmcnt(4), barrier}.
// Swizzle (within 128B row-pair): phys = L ^ (rp&7), L = (row&1)*4+slot16.
// LDS writes linear (global_load_lds); global SOURCE pre-swizzled (s3w).
__global__ void __launch_bounds__(512, 2)
gemm8_bf16(const unsigned short* __restrict__ A,   // [M][K] bf16 bits
           const unsigned short* __restrict__ B,   // [N][K] bf16 bits
           const float* __restrict__ bias,         // [N]
           float* __restrict__ C) {                // [M][N] f32
    extern __shared__ unsigned short lds[];
    unsigned short* __restrict__ Au = lds;            // 4 * 8192 elems
    unsigned short* __restrict__ Bu = lds + 32768;    // 4 * 8192 elems

    const int tid  = threadIdx.x;
    const int lane = tid & 63;
    const int wave = tid >> 6;

    // T1: XCD-aware bijective swizzle (nwg = 512, % 8 == 0)
    const int bid = blockIdx.x;
    const int swz = (bid & 7) * 64 + (bid >> 3);
    const int brow = (swz >> 4) * BM;
    const int bcol = (swz & 15) * BN;

    const int wrow = (wave >> 2) * 128;        // wave output rows (2 halves)
    const int wcol = (wave & 3) * 64;          // wave output cols

    // 32x32x16 fragment lane decomposition:
    //   A: row = lane&31, k = (lane>>5)*8 + j   (B same over out-cols)
    const int cl = lane & 31;                  // fragment row/col
    const int h  = lane >> 5;                  // k-subgroup (0,1)

    // read-side swizzle: rp = row>>1 (row-pair), L = (row&1)*4 + slot16,
    // phys = L ^ (rp&7). ksl (k-slice within 32-k unit) flips bit1 of L
    // -> addr XOR 32.
    const int rl_half = cl >> 1;
    const int physA0  = (((lane & 1) << 2) | h) ^ (rl_half & 7);
    const int abase0  = wrow * 64 + rl_half * 128 + physA0 * 16;  // bytes
    const int bbase0  = wcol * 64 + rl_half * 128 + physA0 * 16;  // bytes

    // write-side: lane's linear LDS slot -> logical (row, col) in global
    const int l8 = lane & 7, lh = lane >> 3;
    const int s3w    = l8 ^ lh;
    const int wrow_l = 2 * lh + (s3w >> 2);    // row within 16-row call block
    const int wcol_l = (s3w & 3) * 8;          // bf16 col within 32-col unit

    const unsigned short* __restrict__ Ag = A + (size_t)brow * K;
    const unsigned short* __restrict__ Bg = B + (size_t)bcol * K;

    f32x16 acc[4][2];
#pragma unroll
    for (int mf = 0; mf < 4; ++mf)
#pragma unroll
        for (int nf = 0; nf < 2; ++nf)
#pragma unroll
            for (int r = 0; r < 16; ++r) acc[mf][nf][r] = 0.0f;

    bf16x8 af[4][2], bf[2][2];

#define STG1(dst, src) __builtin_amdgcn_global_load_lds(GLOBAL_AS(src), LDS_AS(dst), 16, 0, 0)
#define STGA(slot, kcol) do {                                                   \
    STG1(Au + (slot) * 8192 + wave * 512,                                       \
         Ag + (size_t)(wave * 16 + wrow_l) * K + (kcol) + wcol_l);              \
    STG1(Au + (slot) * 8192 + (wave + 8) * 512,                                 \
         Ag + (size_t)((wave + 8) * 16 + wrow_l) * K + (kcol) + wcol_l);        \
  } while (0)
#define STGB(slot, kcol) do {                                                   \
    STG1(Bu + (slot) * 8192 + wave * 512,                                       \
         Bg + (size_t)(wave * 16 + wrow_l) * K + (kcol) + wcol_l);              \
    STG1(Bu + (slot) * 8192 + (wave + 8) * 512,                                 \
         Bg + (size_t)((wave + 8) * 16 + wrow_l) * K + (kcol) + wcol_l);        \
  } while (0)
#define LDA8(unit) do {                                                         \
    const char* ub_ = (const char*)Au + (unit) * 16384;                         \
    _Pragma("unroll")                                                           \
    for (int mf = 0; mf < 4; ++mf) {                                            \
        af[mf][0] = *(const bf16x8*)(ub_ + (abase0       ) + mf * 2048);        \
        af[mf][1] = *(const bf16x8*)(ub_ + (abase0 ^ 32  ) + mf * 2048);        \
    }                                                                           \
  } while (0)
#define LDB4(unit) do {                                                         \
    const char* vb_ = (const char*)Bu + (unit) * 16384;                         \
    _Pragma("unroll")                                                           \
    for (int nf = 0; nf < 2; ++nf) {                                            \
        bf[nf][0] = *(const bf16x8*)(vb_ + (bbase0       ) + nf * 2048);        \
        bf[nf][1] = *(const bf16x8*)(vb_ + (bbase0 ^ 32  ) + nf * 2048);        \
    }                                                                           \
  } while (0)
#define MM16 do {                                                               \
    __builtin_amdgcn_s_setprio(1);                                              \
    _Pragma("unroll")                                                           \
    for (int ksl = 0; ksl < 2; ++ksl)                                           \
      _Pragma("unroll")                                                         \
      for (int mf = 0; mf < 4; ++mf)                                            \
        _Pragma("unroll")                                                       \
        for (int nf = 0; nf < 2; ++nf)                                          \
          acc[mf][nf] = __builtin_amdgcn_mfma_f32_32x32x16_bf16(                \
              af[mf][ksl], bf[nf][ksl], acc[mf][nf], 0, 0, 0);                  \
    __builtin_amdgcn_s_setprio(0);                                              \
  } while (0)
#define BAR   __builtin_amdgcn_s_barrier()
#define WLGKM asm volatile("s_waitcnt lgkmcnt(0)" ::: "memory")
#define WVM4  asm volatile("s_waitcnt vmcnt(4)" ::: "memory")
#define WVM0  asm volatile("s_waitcnt vmcnt(0)" ::: "memory")

    // prologue: stage tile 0 (kh0->slot0, kh1->slot1); keep kh1 in flight
    STGA(0, 0); STGB(0, 0);
    STGA(1, 32); STGB(1, 32);
    WVM4;           // slot0 done (8 outstanding -> 4)
    BAR;

    for (int t = 0; t < NT; ++t) {
        const int u0 = (2 * t) & 3;
        const int u1 = (2 * t + 1) & 3;
        const int s0 = (2 * t + 2) & 3;
        const int s1 = (2 * t + 3) & 3;
        const int kn = (t + 1 < NT) ? (t + 1) * 64 : 0;   // wrap: benign
        // P1: k-half 0
        LDA8(u0); LDB4(u0);
        STGA(s0, kn); STGB(s0, kn);
        BAR; WLGKM; MM16; WVM4; BAR;    // retires u1(t) stage batch
        // P2: k-half 1
        LDA8(u1); LDB4(u1);
        STGA(s1, kn + 32); STGB(s1, kn + 32);
        BAR; WLGKM; MM16; WVM4; BAR;    // retires u0(t+1) stage batch
    }
    WVM0;   // drain wrapped tail stages

    // epilogue: 32x32 C/D layout (m74/m101): col=lane&31,
    // row = (reg&3) + 8*(reg>>2) + 4*(lane>>5)
    float bv[2];
#pragma unroll
    for (int nf = 0; nf < 2; ++nf) bv[nf] = bias[bcol + wcol + nf * 32 + cl];
#pragma unroll
    for (int mf = 0; mf < 4; ++mf) {
#pragma unroll
        for (int r = 0; r < 16; ++r) {
            const int row = brow + wrow + mf * 32 + (r & 3) + 8 * (r >> 2) + 4 * h;
            float* crow = C + (size_t)row * N + bcol + wcol + cl;
            crow[0]  = acc[mf][0][r] + bv[0];
            crow[32] = acc[mf][1][r] + bv[1];
        }
    }
#undef STG1
#undef STGA
#undef STGB
#undef LDA8
#undef LDB4
#undef MM16
#undef BAR
#undef WLGKM
#undef WVM4
#undef WVM0
}

// ---- fallback (only if ws too small): f32 vector GEMM ----
__global__ void fallback_gemm(const float* __restrict__ x,
                              const float* __restrict__ w,
                              const int* __restrict__ mask,
                              const float* __restrict__ bias,
                              float* __restrict__ C) {
    const int tid = threadIdx.x;
    const int tx = tid & 15, ty = tid >> 4;
    const int brow = blockIdx.y * 64, bcol = blockIdx.x * 64;
    __shared__ float As[64][17];
    __shared__ float Ws[64][17];
    float acc[4][4] = {};
    for (int k0 = 0; k0 < K; k0 += 16) {
        __syncthreads();
        for (int i = tid; i < 64 * 16; i += 256) {
            int r = i >> 4, c = i & 15;
            As[r][c] = x[(size_t)(brow + r) * K + k0 + c];
            float wv = w[(size_t)(bcol + r) * K + k0 + c];
            Ws[r][c] = mask[(size_t)(bcol + r) * K + k0 + c] ? wv : 0.0f;
        }
        __syncthreads();
        for (int kk = 0; kk < 16; ++kk) {
            float a[4], b[4];
#pragma unroll
            for (int i = 0; i < 4; ++i) a[i] = As[ty * 4 + i][kk];
#pragma unroll
            for (int i = 0; i < 4; ++i) b[i] = Ws[tx * 4 + i][kk];
#pragma unroll
            for (int i = 0; i < 4; ++i)
#pragma unroll
                for (int j = 0; j < 4; ++j) acc[i][j] += a[i] * b[j];
        }
    }
    for (int i = 0; i < 4; ++i)
        for (int j = 0; j < 4; ++j) {
            int row = brow + ty * 4 + i, col = bcol + tx * 4 + j;
            C[(size_t)row * N + col] = acc[i][j] + bias[col];
        }
}

extern "C" void kernel_launch(void* const* d_in, const int* in_sizes, int n_in,
                              void* d_out, int out_size, void* d_ws, size_t ws_size,
                              hipStream_t stream) {
    const float* x    = (const float*)d_in[0];
    const float* w    = (const float*)d_in[1];
    const float* bias = (const float*)d_in[2];
    const int*   mask = (const int*)d_in[3];
    float* out = (float*)d_out;

    const size_t need = ((size_t)M * K + (size_t)N * K) * sizeof(unsigned short);
    if (ws_size >= need) {
        unsigned short* xb = (unsigned short*)d_ws;           // [M][K] bf16
        unsigned short* wb = xb + (size_t)M * K;              // [N][K] bf16
        (void)hipFuncSetAttribute((const void*)gemm8_bf16,
                                  hipFuncAttributeMaxDynamicSharedMemorySize,
                                  131072);
        cvt_x_kernel<<<(M * K / 4) / 256, 256, 0, stream>>>(x, xb);
        cvt_wm_kernel<<<(N * K / 4) / 256, 256, 0, stream>>>(w, mask, wb);
        gemm8_bf16<<<(M / BM) * (N / BN), 512, 131072, stream>>>(xb, wb, bias, out);
    } else {
        dim3 g(N / 64, M / 64);
        fallback_gemm<<<g, 256, 0, stream>>>(x, w, mask, bias, out);
    }
}

// Round 6
// 299.976 us; speedup vs baseline: 1.1670x; 1.1259x over previous
//
#include <hip/hip_runtime.h>
#include <hip/hip_bf16.h>
#include <stdint.h>

// ExpanderLinear: y[t,o] = sum_i x[t,i] * (w[o,i]*mask[o,i]) + bias[o]
// M=8192, K=4096, N=4096. f32 in/out, bf16 MFMA compute.
// GEMM: R2 structure (best: 263us): 256x256 tile, 8 waves, ring-4 half-K LDS
// units, 4 phases/K-tile, counted vmcnt(4), T1+T2+T5.
// R6 change: NO forced lgkmcnt(0) before MFMA clusters -- let the compiler
// emit fine-grained per-use lgkm waits so LDS reads overlap MFMA issue.
// Compiler memory fences after each s_barrier prevent load hoisting.

typedef __attribute__((ext_vector_type(4))) float          f32x4;
typedef __attribute__((ext_vector_type(4))) int            i32x4;
typedef __attribute__((ext_vector_type(4))) unsigned short u16x4;
typedef __attribute__((ext_vector_type(8))) __bf16         bf16x8;

static constexpr int M = 8192;
static constexpr int N = 4096;
static constexpr int K = 4096;

#define BM 256
#define BN 256
#define NT (K / 64)

#define GLOBAL_AS(p) ((const __attribute__((address_space(1))) void*)(p))
#define LDS_AS(p)    ((__attribute__((address_space(3))) void*)(p))

__device__ __forceinline__ unsigned short f2bf(float f) {
    unsigned int u = __float_as_uint(f);
    u = (u + 0x7fffu + ((u >> 16) & 1u)) >> 16;
    return (unsigned short)u;
}

// ---- prep 1: x f32 -> bf16 ----
__global__ void cvt_x_kernel(const float* __restrict__ x,
                             unsigned short* __restrict__ out) {
    int i = blockIdx.x * blockDim.x + threadIdx.x;
    f32x4 v = ((const f32x4*)x)[i];
    u16x4 r;
    r.x = f2bf(v.x); r.y = f2bf(v.y); r.z = f2bf(v.z); r.w = f2bf(v.w);
    ((u16x4*)out)[i] = r;
}

// ---- prep 2: (w * mask) f32 -> bf16, fused ----
__global__ void cvt_wm_kernel(const float* __restrict__ w,
                              const int* __restrict__ mask,
                              unsigned short* __restrict__ out) {
    int i = blockIdx.x * blockDim.x + threadIdx.x;
    f32x4 v = ((const f32x4*)w)[i];
    i32x4 m = ((const i32x4*)mask)[i];
    u16x4 r;
    r.x = m.x ? f2bf(v.x) : (unsigned short)0;
    r.y = m.y ? f2bf(v.y) : (unsigned short)0;
    r.z = m.z ? f2bf(v.z) : (unsigned short)0;
    r.w = m.w ? f2bf(v.w) : (unsigned short)0;
    ((u16x4*)out)[i] = r;
}

// ---- main GEMM ----
// LDS: A-ring = 4 units of [256 rows][32 bf16] (16KB each), B-ring same.
// Unit for (tile t, k-half h) lives in slot (2t+h)&3.
// Swizzle (within 128B row-pair): phys3 = (((row&1)<<2)|fq) ^ ((row>>1)&7).
// LDS writes stay linear (global_load_lds); global SOURCE pre-swizzled.
__global__ void __launch_bounds__(512, 2)
gemm8_bf16(const unsigned short* __restrict__ A,   // [M][K] bf16 bits
           const unsigned short* __restrict__ B,   // [N][K] bf16 bits
           const float* __restrict__ bias,         // [N]
           float* __restrict__ C) {                // [M][N] f32
    extern __shared__ unsigned short lds[];
    unsigned short* __restrict__ Au = lds;            // 4 * 8192 elems
    unsigned short* __restrict__ Bu = lds + 32768;    // 4 * 8192 elems

    const int tid  = threadIdx.x;
    const int lane = tid & 63;
    const int wave = tid >> 6;

    // T1: XCD-aware bijective swizzle (nwg = 512, % 8 == 0)
    const int bid = blockIdx.x;
    const int swz = (bid & 7) * 64 + (bid >> 3);
    const int brow = (swz >> 4) * BM;          // ntn = 16
    const int bcol = (swz & 15) * BN;

    const int wrow = (wave >> 2) * 128;        // wave output rows
    const int wcol = (wave & 3) * 64;          // wave output cols
    const int fr = lane & 15;                  // fragment row/col
    const int fq = lane >> 4;                  // k-subgroup

    // read-side swizzle bases (byte offsets within a unit)
    const int s3r   = (((fr & 1) << 2) | fq) ^ (fr >> 1);
    const int abase = wrow * 64 + (fr >> 1) * 128 + s3r * 16;   // + m*1024
    const int bbase = wcol * 64 + (fr >> 1) * 128 + s3r * 16;   // + n*1024

    // write-side: lane's linear LDS slot -> logical (row, col) in global
    const int l8 = lane & 7, lh = lane >> 3;
    const int s3w    = l8 ^ lh;
    const int wrow_l = 2 * lh + (s3w >> 2);    // row within 16-row call block
    const int wcol_l = (s3w & 3) * 8;          // bf16 col within 32-col unit

    const unsigned short* __restrict__ Ag = A + (size_t)brow * K;
    const unsigned short* __restrict__ Bg = B + (size_t)bcol * K;

    f32x4 acc[8][4];
#pragma unroll
    for (int m = 0; m < 8; ++m)
#pragma unroll
        for (int n = 0; n < 4; ++n) acc[m][n] = (f32x4)(0.0f);

    bf16x8 af[4], bfv[4];

#define STG1(dst, src) __builtin_amdgcn_global_load_lds(GLOBAL_AS(src), LDS_AS(dst), 16, 0, 0)
#define STGA(slot, kcol) do {                                                   \
    STG1(Au + (slot) * 8192 + wave * 512,                                       \
         Ag + (size_t)(wave * 16 + wrow_l) * K + (kcol) + wcol_l);              \
    STG1(Au + (slot) * 8192 + (wave + 8) * 512,                                 \
         Ag + (size_t)((wave + 8) * 16 + wrow_l) * K + (kcol) + wcol_l);        \
  } while (0)
#define STGB(slot, kcol) do {                                                   \
    STG1(Bu + (slot) * 8192 + wave * 512,                                       \
         Bg + (size_t)(wave * 16 + wrow_l) * K + (kcol) + wcol_l);              \
    STG1(Bu + (slot) * 8192 + (wave + 8) * 512,                                 \
         Bg + (size_t)((wave + 8) * 16 + wrow_l) * K + (kcol) + wcol_l);        \
  } while (0)
#define LDA4(unit, m0) do {                                                     \
    const char* ub_ = (const char*)(Au + (unit) * 8192);                        \
    _Pragma("unroll")                                                           \
    for (int i = 0; i < 4; ++i)                                                 \
        af[i] = *(const bf16x8*)(ub_ + abase + ((m0) + i) * 1024);              \
  } while (0)
#define LDB4(unit) do {                                                         \
    const char* vb_ = (const char*)(Bu + (unit) * 8192);                        \
    _Pragma("unroll")                                                           \
    for (int n = 0; n < 4; ++n)                                                 \
        bfv[n] = *(const bf16x8*)(vb_ + bbase + n * 1024);                      \
  } while (0)
#define MM4(r0) do {                                                            \
    __builtin_amdgcn_s_setprio(1);                                              \
    _Pragma("unroll")                                                           \
    for (int i = 0; i < 4; ++i)                                                 \
      _Pragma("unroll")                                                         \
      for (int n = 0; n < 4; ++n)                                               \
        acc[(r0) + i][n] = __builtin_amdgcn_mfma_f32_16x16x32_bf16(             \
            af[i], bfv[n], acc[(r0) + i][n], 0, 0, 0);                          \
    __builtin_amdgcn_s_setprio(0);                                              \
  } while (0)
#define BAR   __builtin_amdgcn_s_barrier()
#define FENCE asm volatile("" ::: "memory")
#define WVM4  asm volatile("s_waitcnt vmcnt(4)" ::: "memory")
#define WVM0  asm volatile("s_waitcnt vmcnt(0)" ::: "memory")

    // prologue: stage tile 0 (kh0->slot0, kh1->slot1); keep kh1 in flight
    STGA(0, 0); STGB(0, 0);
    STGA(1, 32); STGB(1, 32);
    WVM4;   // slot0 complete (8 outstanding -> 4)
    BAR; FENCE;

    for (int t = 0; t < NT - 1; ++t) {
        const int u0 = (2 * t) & 3;
        const int u1 = (2 * t + 1) & 3;
        const int s0 = (2 * t + 2) & 3;   // stage slots for tile t+1
        const int s1 = (2 * t + 3) & 3;
        const int kn = (t + 1) * 64;
        // P1: n-pair 0 x kh0 (no forced lgkm drain: compiler emits per-use waits)
        LDA4(u0, 0); LDB4(u0); STGA(s0, kn);
        BAR; FENCE; MM4(0);
        BAR; FENCE;
        // P2: rows 4-7 x kh0 (bfv reused); retire this tile's kh1 stage batch
        LDA4(u0, 4); STGB(s0, kn);
        BAR; FENCE; MM4(4); WVM4;
        BAR; FENCE;
        // P3: u1, rows 0-3
        LDA4(u1, 0); LDB4(u1); STGA(s1, kn + 32);
        BAR; FENCE; MM4(0);
        BAR; FENCE;
        // P4: u1, rows 4-7; retire next tile's kh0 stage batch
        LDA4(u1, 4); STGB(s1, kn + 32);
        BAR; FENCE; MM4(4); WVM4;
        BAR; FENCE;
    }
    {   // last tile: no staging; drain
        const int u0 = (2 * (NT - 1)) & 3;
        const int u1 = (2 * (NT - 1) + 1) & 3;
        LDA4(u0, 0); LDB4(u0);
        BAR; FENCE; MM4(0);
        BAR; FENCE;
        LDA4(u0, 4);
        BAR; FENCE; MM4(4); WVM0;
        BAR; FENCE;
        LDA4(u1, 0); LDB4(u1);
        BAR; FENCE; MM4(0);
        BAR; FENCE;
        LDA4(u1, 4);
        FENCE; MM4(4);
    }

    // epilogue: C/D layout col=lane&15, row=(lane>>4)*4+reg [m89/m91]
    float bv[4];
#pragma unroll
    for (int n = 0; n < 4; ++n) bv[n] = bias[bcol + wcol + n * 16 + fr];
#pragma unroll
    for (int m = 0; m < 8; ++m) {
#pragma unroll
        for (int j = 0; j < 4; ++j) {
            const int row = brow + wrow + m * 16 + fq * 4 + j;
            float* crow = C + (size_t)row * N + bcol + wcol + fr;
#pragma unroll
            for (int n = 0; n < 4; ++n) crow[n * 16] = acc[m][n][j] + bv[n];
        }
    }
#undef STG1
#undef STGA
#undef STGB
#undef LDA4
#undef LDB4
#undef MM4
#undef BAR
#undef FENCE
#undef WVM4
#undef WVM0
}

// ---- fallback (only if ws too small): f32 vector GEMM ----
__global__ void fallback_gemm(const float* __restrict__ x,
                              const float* __restrict__ w,
                              const int* __restrict__ mask,
                              const float* __restrict__ bias,
                              float* __restrict__ C) {
    const int tid = threadIdx.x;
    const int tx = tid & 15, ty = tid >> 4;
    const int brow = blockIdx.y * 64, bcol = blockIdx.x * 64;
    __shared__ float As[64][17];
    __shared__ float Ws[64][17];
    float acc[4][4] = {};
    for (int k0 = 0; k0 < K; k0 += 16) {
        __syncthreads();
        for (int i = tid; i < 64 * 16; i += 256) {
            int r = i >> 4, c = i & 15;
            As[r][c] = x[(size_t)(brow + r) * K + k0 + c];
            float wv = w[(size_t)(bcol + r) * K + k0 + c];
            Ws[r][c] = mask[(size_t)(bcol + r) * K + k0 + c] ? wv : 0.0f;
        }
        __syncthreads();
        for (int kk = 0; kk < 16; ++kk) {
            float a[4], b[4];
#pragma unroll
            for (int i = 0; i < 4; ++i) a[i] = As[ty * 4 + i][kk];
#pragma unroll
            for (int i = 0; i < 4; ++i) b[i] = Ws[tx * 4 + i][kk];
#pragma unroll
            for (int i = 0; i < 4; ++i)
#pragma unroll
                for (int j = 0; j < 4; ++j) acc[i][j] += a[i] * b[j];
        }
    }
    for (int i = 0; i < 4; ++i)
        for (int j = 0; j < 4; ++j) {
            int row = brow + ty * 4 + i, col = bcol + tx * 4 + j;
            C[(size_t)row * N + col] = acc[i][j] + bias[col];
        }
}

extern "C" void kernel_launch(void* const* d_in, const int* in_sizes, int n_in,
                              void* d_out, int out_size, void* d_ws, size_t ws_size,
                              hipStream_t stream) {
    const float* x    = (const float*)d_in[0];
    const float* w    = (const float*)d_in[1];
    const float* bias = (const float*)d_in[2];
    const int*   mask = (const int*)d_in[3];
    float* out = (float*)d_out;

    const size_t need = ((size_t)M * K + (size_t)N * K) * sizeof(unsigned short);
    if (ws_size >= need) {
        unsigned short* xb = (unsigned short*)d_ws;           // [M][K] bf16
        unsigned short* wb = xb + (size_t)M * K;              // [N][K] bf16
        (void)hipFuncSetAttribute((const void*)gemm8_bf16,
                                  hipFuncAttributeMaxDynamicSharedMemorySize,
                                  131072);
        cvt_x_kernel<<<(M * K / 4) / 256, 256, 0, stream>>>(x, xb);
        cvt_wm_kernel<<<(N * K / 4) / 256, 256, 0, stream>>>(w, mask, wb);
        gemm8_bf16<<<(M / BM) * (N / BN), 512, 131072, stream>>>(xb, wb, bias, out);
    } else {
        dim3 g(N / 64, M / 64);
        fallback_gemm<<<g, 256, 0, stream>>>(x, w, mask, bias, out);
    }
}